// Round 10
// baseline (316.591 us; speedup 1.0000x reference)
//
#include <hip/hip_runtime.h>
#include <hip/hip_bf16.h>
#include <math.h>

typedef __bf16 bf16;
typedef __attribute__((ext_vector_type(8))) bf16 bf16x8;
typedef __attribute__((ext_vector_type(2))) bf16 bf16x2;
typedef __attribute__((ext_vector_type(4))) float f32x4;

#define LOG2E 1.4426950408889634f
#define LOG2_THETA 18.931568569324174f   // log2(500000)

#if __has_builtin(__builtin_amdgcn_exp2f)
#define EXP2F __builtin_amdgcn_exp2f
#else
#define EXP2F exp2f
#endif

// ---- async global->LDS 16B copy (lane-scattered: lds_base + lane*16) ----
__device__ inline void async_cp16(const void* gptr, void* lptr) {
  __builtin_amdgcn_global_load_lds(
      (const __attribute__((address_space(1))) unsigned int*)gptr,
      (__attribute__((address_space(3))) unsigned int*)lptr, 16, 0, 0);
}

// ============================================================
// Fused fp32->bf16 cast of x, wq|wk|wv (contiguous dst), wo.
// 9216 blocks x 256 thr x 8 elems = 18874368 elems total.
// ============================================================
__global__ __launch_bounds__(256) void cast_all(
    const float* __restrict__ x,  const float* __restrict__ wq,
    const float* __restrict__ wk, const float* __restrict__ wv,
    const float* __restrict__ wo, bf16* __restrict__ xb,
    bf16* __restrict__ wqkvb, bf16* __restrict__ wob) {
  const int bx = blockIdx.x;
  const size_t gi = ((size_t)bx * 256 + threadIdx.x) * 8;
  const float* src;
  bf16* dst;
  if (bx < 4096)      { src = x  + gi;              dst = xb + gi; }
  else if (bx < 6144) { src = wq + (gi -  8388608); dst = wqkvb + (gi - 8388608); }
  else if (bx < 6656) { src = wk + (gi - 12582912); dst = wqkvb + 4194304 + (gi - 12582912); }
  else if (bx < 7168) { src = wv + (gi - 13631488); dst = wqkvb + 5242880 + (gi - 13631488); }
  else                { src = wo + (gi - 14680064); dst = wob + (gi - 14680064); }
  float4 a = *(const float4*)(src);
  float4 b = *(const float4*)(src + 4);
  bf16x8 o;
  o[0] = (bf16)a.x; o[1] = (bf16)a.y; o[2] = (bf16)a.z; o[3] = (bf16)a.w;
  o[4] = (bf16)b.x; o[5] = (bf16)b.y; o[6] = (bf16)b.z; o[7] = (bf16)b.w;
  *(bf16x8*)dst = o;
}

// ============================================================
// GEMM core — R10 structure (2-phase pipelined K-loop + bijective
// XCD swizzle). Neutral vs m97-class baseline per m99/m100, kept.
// ============================================================
template <typename OUT_T, bool QKV, bool CLIP>
__global__ __launch_bounds__(256) void gemm_bt(
    const bf16* __restrict__ A, const bf16* __restrict__ W,
    const float* __restrict__ b0, const float* __restrict__ b1,
    const float* __restrict__ b2, OUT_T* __restrict__ C,
    int M, int N, int K) {
  __shared__ bf16 As[2][128 * 32];   // 8 KB per half
  __shared__ bf16 Bs[2][128 * 32];
  const int nwg = gridDim.x * gridDim.y;
  int lid = blockIdx.x + gridDim.x * blockIdx.y;
  lid = (lid & 7) * (nwg >> 3) + (lid >> 3);   // XCD-chunked, bijective
  const int m0 = (lid & 31) * 128, n0 = (lid >> 5) * 128;  // gridDim.x==32
  const int t = threadIdx.x;
  const int w = t >> 6, lane = t & 63, quad = lane >> 4, l15 = lane & 15;
  const int wm = (w >> 1) * 64, wn = (w & 1) * 64;

  f32x4 acc[4][4];
#pragma unroll
  for (int i = 0; i < 4; i++)
#pragma unroll
    for (int j = 0; j < 4; j++) acc[i][j] = (f32x4)0.0f;

  int soff[2], ldso[2];
#pragma unroll
  for (int i = 0; i < 2; i++) {
    const int c = w * 128 + i * 64 + lane;
    const int r = c >> 2;
    const int sl = (c & 3) ^ (r & 3);
    soff[i] = r * K + sl * 8;
    ldso[i] = (w * 128 + i * 64) * 16;
  }
  const bf16* Abase = A + (size_t)m0 * K;
  const bf16* Wbase = W + (size_t)n0 * K;

  const int fseg = (quad ^ (l15 & 3)) * 8;

#pragma unroll
  for (int i = 0; i < 2; i++) {
    async_cp16(Abase + soff[i], (char*)&As[0][0] + ldso[i]);
    async_cp16(Wbase + soff[i], (char*)&Bs[0][0] + ldso[i]);
  }
  __asm__ volatile("s_waitcnt vmcnt(0)" ::: "memory");
  __builtin_amdgcn_s_barrier();
  __builtin_amdgcn_sched_barrier(0);

  int cur = 0;
  for (int k0 = 0; k0 < K; k0 += 32) {
    if (k0 + 32 < K) {
      const int nxt = cur ^ 1;
#pragma unroll
      for (int i = 0; i < 2; i++) {
        async_cp16(Abase + k0 + 32 + soff[i], (char*)&As[nxt][0] + ldso[i]);
        async_cp16(Wbase + k0 + 32 + soff[i], (char*)&Bs[nxt][0] + ldso[i]);
      }
    }
    __builtin_amdgcn_sched_barrier(0);

    bf16x8 af[4], bfr[4];
#pragma unroll
    for (int i = 0; i < 4; i++)
      af[i] = *(const bf16x8*)(&As[cur][0] + (wm + i * 16 + l15) * 32 + fseg);
#pragma unroll
    for (int j = 0; j < 4; j++)
      bfr[j] = *(const bf16x8*)(&Bs[cur][0] + (wn + j * 16 + l15) * 32 + fseg);
#pragma unroll
    for (int i = 0; i < 4; i++)
#pragma unroll
      for (int j = 0; j < 4; j++)
        acc[i][j] = __builtin_amdgcn_mfma_f32_16x16x32_bf16(af[i], bfr[j], acc[i][j], 0, 0, 0);

    __asm__ volatile("s_waitcnt vmcnt(0)" ::: "memory");
    __builtin_amdgcn_s_barrier();
    __builtin_amdgcn_sched_barrier(0);
    cur ^= 1;
  }

#pragma unroll
  for (int i = 0; i < 4; i++)
#pragma unroll
    for (int j = 0; j < 4; j++) {
      const int col = n0 + wn + j * 16 + l15;
      float bval;
      if (QKV) {
        if (col < 2048) bval = b0[col];
        else if (col < 2560) bval = b1[col - 2048];
        else bval = b2[col - 2560];
      } else {
        bval = b0[col];
      }
#pragma unroll
      for (int r = 0; r < 4; r++) {
        const int row = m0 + wm + i * 16 + quad * 4 + r;
        float v = acc[i][j][r] + bval;
        if (CLIP) v = fminf(fmaxf(v, -8.0f), 8.0f);
        C[(size_t)row * N + col] = (OUT_T)v;
      }
    }
}

// ============================================================
// Fused mid stage — R9 structure. Roles by blockIdx.x:
//   [0,4096)    : LN+RoPE q  (1 row/block)          -> Qr[b][h][t][d]
//   [4096,5120) : LN+RoPE k  (4 rows/block, 1/wave) -> Kr[b][kv][t][d]
//   [5120,5376) : V transpose                       -> Vt[b][kv][d][t]
// ============================================================
__global__ __launch_bounds__(256) void fused_mid(
    const bf16* __restrict__ X, const float* __restrict__ qg,
    const float* __restrict__ qb, const float* __restrict__ kg,
    const float* __restrict__ kb, bf16* __restrict__ Qr,
    bf16* __restrict__ Kr, bf16* __restrict__ Vt) {
  __shared__ bf16 smt[64][136];
  __shared__ float red[8];
  __shared__ float tcs[64], tsn[64];
  __shared__ float ktab_c[4][64], ktab_s[4][64];
  const int bx = blockIdx.x;
  const int tid = threadIdx.x;
  const int w = tid >> 6, lane = tid & 63;

  if (bx < 4096) {
    // ---- LN + RoPE q (one 2048-dim row per block) ----
    const int row = bx, b = row >> 11, tpos = row & 2047;
    if (tid < 64) {
      const float inv = exp2f((float)tid * (-LOG2_THETA / 64.0f));
      float sn, cs;
      sincosf((float)tpos * inv, &sn, &cs);
      tcs[tid] = cs; tsn[tid] = sn;
    }
    const bf16* x = X + (size_t)row * 3072;
    bf16x8 xi = *(const bf16x8*)(x + tid * 8);
    float v[8];
    float s = 0.0f;
#pragma unroll
    for (int e = 0; e < 8; e++) { v[e] = (float)xi[e]; s += v[e]; }
#pragma unroll
    for (int m = 32; m >= 1; m >>= 1) s += __shfl_xor(s, m, 64);
    if (lane == 0) red[w] = s;
    __syncthreads();
    const float mean = (red[0] + red[1] + red[2] + red[3]) * (1.0f / 2048.0f);
    float vs = 0.0f;
#pragma unroll
    for (int e = 0; e < 8; e++) { float d = v[e] - mean; vs += d * d; }
#pragma unroll
    for (int m = 32; m >= 1; m >>= 1) vs += __shfl_xor(vs, m, 64);
    if (lane == 0) red[4 + w] = vs;
    __syncthreads();
    const float var = (red[4] + red[5] + red[6] + red[7]) * (1.0f / 2048.0f);
    const float rstd = rsqrtf(var + 1e-5f);
    const int c0 = tid * 8;
    const float4 g0 = *(const float4*)(qg + c0);
    const float4 g1 = *(const float4*)(qg + c0 + 4);
    const float4 b0v = *(const float4*)(qb + c0);
    const float4 b1v = *(const float4*)(qb + c0 + 4);
    const float gA[8] = {g0.x, g0.y, g0.z, g0.w, g1.x, g1.y, g1.z, g1.w};
    const float bA[8] = {b0v.x, b0v.y, b0v.z, b0v.w, b1v.x, b1v.y, b1v.z, b1v.w};
    float y[8];
#pragma unroll
    for (int e = 0; e < 8; e++) y[e] = (v[e] - mean) * rstd * gA[e] + bA[e];
    const int h = c0 >> 7;
    bf16x8 ov;
#pragma unroll
    for (int e = 0; e < 8; e++) {
      const int c = c0 + e, d = c & 127, i = d & 63;
      const float part = __shfl_xor(y[e], 8, 64);
      const float rot = (d < 64) ? -part : part;
      ov[e] = (bf16)(y[e] * tcs[i] + rot * tsn[i]);
    }
    *(bf16x8*)(Qr + ((size_t)(b * 16 + h) * 2048 + tpos) * 128 + (c0 & 127)) = ov;
  } else if (bx < 5120) {
    // ---- LN + RoPE k: 4 rows/block, one 512-dim row per wave ----
    const int idx = bx - 4096;
    const int row = idx * 4 + w, b = row >> 11, tpos = row & 2047;
    {
      const float inv = exp2f((float)lane * (-LOG2_THETA / 64.0f));
      float sn, cs;
      sincosf((float)tpos * inv, &sn, &cs);
      ktab_c[w][lane] = cs; ktab_s[w][lane] = sn;
    }
    __syncthreads();
    const bf16* x = X + (size_t)row * 3072 + 2048;
    bf16x8 xi = *(const bf16x8*)(x + lane * 8);
    float v[8];
    float s = 0.0f;
#pragma unroll
    for (int e = 0; e < 8; e++) { v[e] = (float)xi[e]; s += v[e]; }
#pragma unroll
    for (int m = 32; m >= 1; m >>= 1) s += __shfl_xor(s, m, 64);
    const float mean = s * (1.0f / 512.0f);
    float vs = 0.0f;
#pragma unroll
    for (int e = 0; e < 8; e++) { float d = v[e] - mean; vs += d * d; }
#pragma unroll
    for (int m = 32; m >= 1; m >>= 1) vs += __shfl_xor(vs, m, 64);
    const float var = vs * (1.0f / 512.0f);
    const float rstd = rsqrtf(var + 1e-5f);
    const int c0 = lane * 8;
    const float4 g0 = *(const float4*)(kg + c0);
    const float4 g1 = *(const float4*)(kg + c0 + 4);
    const float4 b0v = *(const float4*)(kb + c0);
    const float4 b1v = *(const float4*)(kb + c0 + 4);
    const float gA[8] = {g0.x, g0.y, g0.z, g0.w, g1.x, g1.y, g1.z, g1.w};
    const float bA[8] = {b0v.x, b0v.y, b0v.z, b0v.w, b1v.x, b1v.y, b1v.z, b1v.w};
    float y[8];
#pragma unroll
    for (int e = 0; e < 8; e++) y[e] = (v[e] - mean) * rstd * gA[e] + bA[e];
    const int kv = c0 >> 7;
    bf16x8 ov;
#pragma unroll
    for (int e = 0; e < 8; e++) {
      const int c = c0 + e, d = c & 127, i = d & 63;
      const float part = __shfl_xor(y[e], 8, 64);
      const float rot = (d < 64) ? -part : part;
      ov[e] = (bf16)(y[e] * ktab_c[w][i] + rot * ktab_s[w][i]);
    }
    *(bf16x8*)(Kr + ((size_t)(b * 4 + kv) * 2048 + tpos) * 128 + (c0 & 127)) = ov;
  } else {
    // ---- V transpose ----
    const int idx = bx - 5120;
    const int b = idx >> 7, kv = (idx >> 5) & 3, t0 = (idx & 31) * 64;
#pragma unroll
    for (int i = 0; i < 4; i++) {
      const int c = i * 256 + tid;
      const int r = c >> 4, d8 = (c & 15) * 8;
      *(bf16x8*)&smt[r][d8] =
          *(const bf16x8*)(X + (size_t)(b * 2048 + t0 + r) * 3072 + 2560 + kv * 128 + d8);
    }
    __syncthreads();
#pragma unroll
    for (int i = 0; i < 4; i++) {
      const int c = i * 256 + tid;
      const int d = c >> 3, t8 = (c & 7) * 8;
      bf16x8 o;
#pragma unroll
      for (int j = 0; j < 8; j++) o[j] = smt[t8 + j][d];
      *(bf16x8*)(Vt + (size_t)((b * 4 + kv) * 128 + d) * 2048 + t0 + t8) = o;
    }
  }
}

// ============================================================
// Flash attention — R11: single-barrier double-buffered LDS.
//  Per tile kt:
//    write regs(kt+1) -> buf^1   (overlaps QK/PV reads of buf)
//    issue loads(kt+2) -> regs   (in flight across the barrier)
//    QK -> SM -> PV from buf
//    s_waitcnt lgkmcnt(0); s_barrier; sched_barrier(0)
//  ONE barrier per tile. Hazard is lgkm (ds_write), hand-waited —
//  compiler's LDS-DMA vmcnt(0) alias drain (R4's killer) never
//  applies since global loads land in registers. setprio(1) around
//  MFMA clusters (m191 regime: 2 independent out-of-phase blocks/CU).
//  LDS: 2x16K (K) + 2x16K (V) + 11K (Ps) = 76800 B; 2 blocks/CU.
//  grid (16,16,2); block p does q-tiles {31-p, p} (uniform 33 k-tiles).
// ============================================================
__global__ __launch_bounds__(256) void flash_attn(
    const bf16* __restrict__ Q, const bf16* __restrict__ Kt,
    const bf16* __restrict__ Vt, bf16* __restrict__ O) {
  const int p = blockIdx.x;
  const int h = blockIdx.y, b = blockIdx.z;
  const int kv = h >> 2;
  const int tid = threadIdx.x;
  const int w = tid >> 6, lane = tid & 63, quad = lane >> 4, l15 = lane & 15;

  __shared__ bf16 Ks[2][64][128];   // 2 x 16 KB
  __shared__ bf16 Vs[2][128][64];   // 2 x 16 KB
  __shared__ bf16 Ps[4][16][88];    // 11 KB (wave-private strips)

  const bf16* Kb = Kt + (size_t)(b * 4 + kv) * 2048 * 128;
  const bf16* Vb = Vt + (size_t)(b * 4 + kv) * 128 * 2048;

  // staging geometry: thread (w,lane), chunk i in 0..3
  //  K: row rt=(w*4+i)*4+(lane>>4); global seg (lane&15); LDS seg ^(rt&15)
  //  V: row d =(w*4+i)*8+(lane>>3); global seg (lane&7);  LDS seg ^(d&7)
  const int ksl = lane & 15, krt = lane >> 4;
  const int vsl = lane & 7,  vdt = lane >> 3;
  int kgo[4], vgo[4], kwo[4], vwo[4];
#pragma unroll
  for (int i = 0; i < 4; i++) {
    const int c = w * 4 + i;
    const int rt = c * 4 + krt;
    kgo[i] = rt * 128 + ksl * 8;
    kwo[i] = rt * 128 + ((ksl ^ (rt & 15)) * 8);   // offset within one K buffer
    const int d = c * 8 + vdt;
    vgo[i] = d * 2048 + vsl * 8;
    vwo[i] = d * 64 + ((vsl ^ (d & 7)) * 8);       // offset within one V buffer
  }

  const float cexp = 0.08838834764831845f * LOG2E;
  bf16x8 ones;
#pragma unroll
  for (int i = 0; i < 8; i++) ones[i] = (bf16)1.0f;

#pragma unroll 1
  for (int pass = 0; pass < 2; pass++) {
    const int qb = (pass == 0) ? (31 - p) : p;
    const int q0 = qb * 64;
    const int nkt = qb + 1;

    const bf16* Qb = Q + ((size_t)(b * 16 + h) * 2048 + q0 + w * 16 + l15) * 128;
    bf16x8 aq[4];
#pragma unroll
    for (int kk = 0; kk < 4; kk++) aq[kk] = *(const bf16x8*)(Qb + kk * 32 + quad * 8);

    f32x4 o[9];
#pragma unroll
    for (int dt = 0; dt < 9; dt++) o[dt] = (f32x4)0.0f;

    // ---- prologue: tile 0 -> regs -> buf0; issue tile 1 loads ----
    bf16x8 kreg[4], vreg[4];
#pragma unroll
    for (int i = 0; i < 4; i++) {
      kreg[i] = *(const bf16x8*)(Kb + kgo[i]);
      vreg[i] = *(const bf16x8*)(Vb + vgo[i]);
    }
#pragma unroll
    for (int i = 0; i < 4; i++) {
      *(bf16x8*)(&Ks[0][0][0] + kwo[i]) = kreg[i];
      *(bf16x8*)(&Vs[0][0][0] + vwo[i]) = vreg[i];
    }
    if (nkt > 1) {
#pragma unroll
      for (int i = 0; i < 4; i++) {
        kreg[i] = *(const bf16x8*)(Kb + (size_t)64 * 128 + kgo[i]);
        vreg[i] = *(const bf16x8*)(Vb + 64 + vgo[i]);
      }
    }
    __asm__ volatile("s_waitcnt lgkmcnt(0)" ::: "memory");
    __builtin_amdgcn_s_barrier();
    __builtin_amdgcn_sched_barrier(0);

#pragma unroll 1
    for (int kt = 0; kt < nkt; kt++) {
      const int cur = kt & 1;
      const int k0 = kt * 64;

      // write tile kt+1 into the other buffer (overlaps this tile's reads)
      if (kt + 1 < nkt) {
        const int nb = cur ^ 1;
        bf16* kdst = &Ks[nb][0][0];
        bf16* vdst = &Vs[nb][0][0];
#pragma unroll
        for (int i = 0; i < 4; i++) {
          *(bf16x8*)(kdst + kwo[i]) = kreg[i];
          *(bf16x8*)(vdst + vwo[i]) = vreg[i];
        }
      }
      // issue tile kt+2 loads (latency hides under compute + next tile)
      if (kt + 2 < nkt) {
#pragma unroll
        for (int i = 0; i < 4; i++) {
          kreg[i] = *(const bf16x8*)(Kb + (size_t)(k0 + 128) * 128 + kgo[i]);
          vreg[i] = *(const bf16x8*)(Vb + (size_t)(k0 + 128) + vgo[i]);
        }
      }

      // ---- QK^T ----
      const bf16* ksrc = &Ks[cur][0][0];
      f32x4 s4[4];
      __builtin_amdgcn_s_setprio(1);
#pragma unroll
      for (int j = 0; j < 4; j++) {
        f32x4 acc = (f32x4)0.0f;
        const int n = j * 16 + l15;
#pragma unroll
        for (int kk = 0; kk < 4; kk++) {
          bf16x8 bk = *(const bf16x8*)(ksrc + n * 128 + (((kk * 4 + quad) ^ l15) * 8));
          acc = __builtin_amdgcn_mfma_f32_16x16x32_bf16(aq[kk], bk, acc, 0, 0, 0);
        }
        s4[j] = acc;
      }
      __builtin_amdgcn_s_setprio(0);

      // ---- softmax (fixed-max) + P -> private LDS strip ----
      const bool diag = (kt == qb);
      const int qrow_base = q0 + w * 16 + quad * 4;
#pragma unroll
      for (int j = 0; j < 4; j++) {
        const int kg = k0 + j * 16 + l15;
#pragma unroll
        for (int r = 0; r < 4; r++) {
          float pv = EXP2F(s4[j][r] * cexp);
          if (diag && kg > qrow_base + r) pv = 0.0f;
          Ps[w][quad * 4 + r][j * 16 + l15] = (bf16)pv;
        }
      }
      __asm__ volatile("s_waitcnt lgkmcnt(0)" ::: "memory");

      // ---- PV (+ denominator via all-ones column) ----
      const bf16* vsrc = &Vs[cur][0][0];
      __builtin_amdgcn_s_setprio(1);
#pragma unroll
      for (int kk = 0; kk < 2; kk++) {
        bf16x8 pa = *(const bf16x8*)&Ps[w][l15][kk * 32 + quad * 8];
#pragma unroll
        for (int dt = 0; dt < 8; dt++) {
          const int d = dt * 16 + l15;
          bf16x8 vb = *(const bf16x8*)(vsrc + d * 64 + (((kk * 4 + quad) ^ (d & 7)) * 8));
          o[dt] = __builtin_amdgcn_mfma_f32_16x16x32_bf16(pa, vb, o[dt], 0, 0, 0);
        }
        o[8] = __builtin_amdgcn_mfma_f32_16x16x32_bf16(pa, ones, o[8], 0, 0, 0);
      }
      __builtin_amdgcn_s_setprio(0);

      // single end-of-tile barrier: all LDS ops (writes of kt+1, reads
      // of kt) retired; global prefetch loads stay in flight.
      __asm__ volatile("s_waitcnt lgkmcnt(0)" ::: "memory");
      __builtin_amdgcn_s_barrier();
      __builtin_amdgcn_sched_barrier(0);
    }

    bf16* Ob = O + ((size_t)(b * 2048 + q0 + w * 16 + quad * 4)) * 2048 + h * 128;
#pragma unroll
    for (int r = 0; r < 4; r++) {
      const float rinv = 1.0f / o[8][r];
#pragma unroll
      for (int dt = 0; dt < 8; dt++)
        Ob[(size_t)r * 2048 + dt * 16 + l15] = (bf16)(o[dt][r] * rinv);
    }
  }
}

// ============================================================
// Launcher — fp32 in/out, bf16 compute. 5 kernel launches.
// ws layout (bytes), total 88080384:
//   xb    bf16[4096x2048] : 0        .. 16777216  (reused as At)
//   wqkvb bf16[3072x2048] : 16777216 .. 29360128
//   wob   bf16[2048x2048] : 29360128 .. 37748736
//   qkvb  bf16[4096x3072] : 37748736 .. 62914560
//   Qr    bf16[2,16,2048,128] : 62914560 .. 79691776
//   Kr    bf16[2, 4,2048,128] : 79691776 .. 83886080
//   Vt    bf16[2, 4,128,2048] : 83886080 .. 88080384
// ============================================================
extern "C" void kernel_launch(void* const* d_in, const int* in_sizes, int n_in,
                              void* d_out, int out_size, void* d_ws, size_t ws_size,
                              hipStream_t stream) {
  const float* x   = (const float*)d_in[0];
  const float* wq  = (const float*)d_in[1];
  const float* bq  = (const float*)d_in[2];
  const float* wk  = (const float*)d_in[3];
  const float* bk  = (const float*)d_in[4];
  const float* wv  = (const float*)d_in[5];
  const float* bv  = (const float*)d_in[6];
  const float* wo  = (const float*)d_in[7];
  const float* bo  = (const float*)d_in[8];
  const float* qg  = (const float*)d_in[9];
  const float* qbt = (const float*)d_in[10];
  const float* kg  = (const float*)d_in[11];
  const float* kbt = (const float*)d_in[12];
  float* out = (float*)d_out;

  char* ws = (char*)d_ws;
  if (ws_size < (size_t)88080384) return;
  bf16* xb    = (bf16*)(ws);
  bf16* wqkvb = (bf16*)(ws + 16777216);
  bf16* wob   = (bf16*)(ws + 29360128);
  bf16* qkvb  = (bf16*)(ws + 37748736);
  bf16* Qr    = (bf16*)(ws + 62914560);
  bf16* Kr    = (bf16*)(ws + 79691776);
  bf16* Vt    = (bf16*)(ws + 83886080);
  bf16* At    = (bf16*)(ws);  // aliases xb — x dead after QKV gemm

  cast_all<<<9216, 256, 0, stream>>>(x, wq, wk, wv, wo, xb, wqkvb, wob);
  gemm_bt<bf16, true, true><<<dim3(32, 24), 256, 0, stream>>>(
      xb, wqkvb, bq, bk, bv, qkvb, 4096, 3072, 2048);
  fused_mid<<<5376, 256, 0, stream>>>(qkvb, qg, qbt, kg, kbt, Qr, Kr, Vt);
  flash_attn<<<dim3(16, 16, 2), 256, 0, stream>>>(Qr, Kr, Vt, At);
  gemm_bt<float, false, false><<<dim3(32, 16), 256, 0, stream>>>(
      At, wob, bo, nullptr, nullptr, out, 4096, 2048, 2048);
}

// Round 11
// 311.742 us; speedup vs baseline: 1.0156x; 1.0156x over previous
//
#include <hip/hip_runtime.h>
#include <hip/hip_bf16.h>
#include <math.h>

typedef __bf16 bf16;
typedef __attribute__((ext_vector_type(8))) bf16 bf16x8;
typedef __attribute__((ext_vector_type(2))) bf16 bf16x2;
typedef __attribute__((ext_vector_type(4))) float f32x4;

#define LOG2E 1.4426950408889634f
#define LOG2_THETA 18.931568569324174f   // log2(500000)

#if __has_builtin(__builtin_amdgcn_exp2f)
#define EXP2F __builtin_amdgcn_exp2f
#else
#define EXP2F exp2f
#endif

// ---- async global->LDS 16B copy (lane-scattered: lds_base + lane*16) ----
__device__ inline void async_cp16(const void* gptr, void* lptr) {
  __builtin_amdgcn_global_load_lds(
      (const __attribute__((address_space(1))) unsigned int*)gptr,
      (__attribute__((address_space(3))) unsigned int*)lptr, 16, 0, 0);
}

// ============================================================
// Fused fp32->bf16 cast of x, wq|wk|wv (contiguous dst), wo.
// 9216 blocks x 256 thr x 8 elems = 18874368 elems total.
// ============================================================
__global__ __launch_bounds__(256) void cast_all(
    const float* __restrict__ x,  const float* __restrict__ wq,
    const float* __restrict__ wk, const float* __restrict__ wv,
    const float* __restrict__ wo, bf16* __restrict__ xb,
    bf16* __restrict__ wqkvb, bf16* __restrict__ wob) {
  const int bx = blockIdx.x;
  const size_t gi = ((size_t)bx * 256 + threadIdx.x) * 8;
  const float* src;
  bf16* dst;
  if (bx < 4096)      { src = x  + gi;              dst = xb + gi; }
  else if (bx < 6144) { src = wq + (gi -  8388608); dst = wqkvb + (gi - 8388608); }
  else if (bx < 6656) { src = wk + (gi - 12582912); dst = wqkvb + 4194304 + (gi - 12582912); }
  else if (bx < 7168) { src = wv + (gi - 13631488); dst = wqkvb + 5242880 + (gi - 13631488); }
  else                { src = wo + (gi - 14680064); dst = wob + (gi - 14680064); }
  float4 a = *(const float4*)(src);
  float4 b = *(const float4*)(src + 4);
  bf16x8 o;
  o[0] = (bf16)a.x; o[1] = (bf16)a.y; o[2] = (bf16)a.z; o[3] = (bf16)a.w;
  o[4] = (bf16)b.x; o[5] = (bf16)b.y; o[6] = (bf16)b.z; o[7] = (bf16)b.w;
  *(bf16x8*)dst = o;
}

// ============================================================
// GEMM core — R10 structure (2-phase pipelined K-loop + bijective
// XCD swizzle).
// ============================================================
template <typename OUT_T, bool QKV, bool CLIP>
__global__ __launch_bounds__(256) void gemm_bt(
    const bf16* __restrict__ A, const bf16* __restrict__ W,
    const float* __restrict__ b0, const float* __restrict__ b1,
    const float* __restrict__ b2, OUT_T* __restrict__ C,
    int M, int N, int K) {
  __shared__ bf16 As[2][128 * 32];   // 8 KB per half
  __shared__ bf16 Bs[2][128 * 32];
  const int nwg = gridDim.x * gridDim.y;
  int lid = blockIdx.x + gridDim.x * blockIdx.y;
  lid = (lid & 7) * (nwg >> 3) + (lid >> 3);   // XCD-chunked, bijective
  const int m0 = (lid & 31) * 128, n0 = (lid >> 5) * 128;  // gridDim.x==32
  const int t = threadIdx.x;
  const int w = t >> 6, lane = t & 63, quad = lane >> 4, l15 = lane & 15;
  const int wm = (w >> 1) * 64, wn = (w & 1) * 64;

  f32x4 acc[4][4];
#pragma unroll
  for (int i = 0; i < 4; i++)
#pragma unroll
    for (int j = 0; j < 4; j++) acc[i][j] = (f32x4)0.0f;

  int soff[2], ldso[2];
#pragma unroll
  for (int i = 0; i < 2; i++) {
    const int c = w * 128 + i * 64 + lane;
    const int r = c >> 2;
    const int sl = (c & 3) ^ (r & 3);
    soff[i] = r * K + sl * 8;
    ldso[i] = (w * 128 + i * 64) * 16;
  }
  const bf16* Abase = A + (size_t)m0 * K;
  const bf16* Wbase = W + (size_t)n0 * K;

  const int fseg = (quad ^ (l15 & 3)) * 8;

#pragma unroll
  for (int i = 0; i < 2; i++) {
    async_cp16(Abase + soff[i], (char*)&As[0][0] + ldso[i]);
    async_cp16(Wbase + soff[i], (char*)&Bs[0][0] + ldso[i]);
  }
  __asm__ volatile("s_waitcnt vmcnt(0)" ::: "memory");
  __builtin_amdgcn_s_barrier();
  __builtin_amdgcn_sched_barrier(0);

  int cur = 0;
  for (int k0 = 0; k0 < K; k0 += 32) {
    if (k0 + 32 < K) {
      const int nxt = cur ^ 1;
#pragma unroll
      for (int i = 0; i < 2; i++) {
        async_cp16(Abase + k0 + 32 + soff[i], (char*)&As[nxt][0] + ldso[i]);
        async_cp16(Wbase + k0 + 32 + soff[i], (char*)&Bs[nxt][0] + ldso[i]);
      }
    }
    __builtin_amdgcn_sched_barrier(0);

    bf16x8 af[4], bfr[4];
#pragma unroll
    for (int i = 0; i < 4; i++)
      af[i] = *(const bf16x8*)(&As[cur][0] + (wm + i * 16 + l15) * 32 + fseg);
#pragma unroll
    for (int j = 0; j < 4; j++)
      bfr[j] = *(const bf16x8*)(&Bs[cur][0] + (wn + j * 16 + l15) * 32 + fseg);
#pragma unroll
    for (int i = 0; i < 4; i++)
#pragma unroll
      for (int j = 0; j < 4; j++)
        acc[i][j] = __builtin_amdgcn_mfma_f32_16x16x32_bf16(af[i], bfr[j], acc[i][j], 0, 0, 0);

    __asm__ volatile("s_waitcnt vmcnt(0)" ::: "memory");
    __builtin_amdgcn_s_barrier();
    __builtin_amdgcn_sched_barrier(0);
    cur ^= 1;
  }

#pragma unroll
  for (int i = 0; i < 4; i++)
#pragma unroll
    for (int j = 0; j < 4; j++) {
      const int col = n0 + wn + j * 16 + l15;
      float bval;
      if (QKV) {
        if (col < 2048) bval = b0[col];
        else if (col < 2560) bval = b1[col - 2048];
        else bval = b2[col - 2560];
      } else {
        bval = b0[col];
      }
#pragma unroll
      for (int r = 0; r < 4; r++) {
        const int row = m0 + wm + i * 16 + quad * 4 + r;
        float v = acc[i][j][r] + bval;
        if (CLIP) v = fminf(fmaxf(v, -8.0f), 8.0f);
        C[(size_t)row * N + col] = (OUT_T)v;
      }
    }
}

// ============================================================
// Fused mid stage — R9 structure. Roles by blockIdx.x:
//   [0,4096)    : LN+RoPE q  (1 row/block)          -> Qr[b][h][t][d]
//   [4096,5120) : LN+RoPE k  (4 rows/block, 1/wave) -> Kr[b][kv][t][d]
//   [5120,5376) : V transpose                       -> Vt[b][kv][d][t]
// ============================================================
__global__ __launch_bounds__(256) void fused_mid(
    const bf16* __restrict__ X, const float* __restrict__ qg,
    const float* __restrict__ qb, const float* __restrict__ kg,
    const float* __restrict__ kb, bf16* __restrict__ Qr,
    bf16* __restrict__ Kr, bf16* __restrict__ Vt) {
  __shared__ bf16 smt[64][136];
  __shared__ float red[8];
  __shared__ float tcs[64], tsn[64];
  __shared__ float ktab_c[4][64], ktab_s[4][64];
  const int bx = blockIdx.x;
  const int tid = threadIdx.x;
  const int w = tid >> 6, lane = tid & 63;

  if (bx < 4096) {
    // ---- LN + RoPE q (one 2048-dim row per block) ----
    const int row = bx, b = row >> 11, tpos = row & 2047;
    if (tid < 64) {
      const float inv = exp2f((float)tid * (-LOG2_THETA / 64.0f));
      float sn, cs;
      sincosf((float)tpos * inv, &sn, &cs);
      tcs[tid] = cs; tsn[tid] = sn;
    }
    const bf16* x = X + (size_t)row * 3072;
    bf16x8 xi = *(const bf16x8*)(x + tid * 8);
    float v[8];
    float s = 0.0f;
#pragma unroll
    for (int e = 0; e < 8; e++) { v[e] = (float)xi[e]; s += v[e]; }
#pragma unroll
    for (int m = 32; m >= 1; m >>= 1) s += __shfl_xor(s, m, 64);
    if (lane == 0) red[w] = s;
    __syncthreads();
    const float mean = (red[0] + red[1] + red[2] + red[3]) * (1.0f / 2048.0f);
    float vs = 0.0f;
#pragma unroll
    for (int e = 0; e < 8; e++) { float d = v[e] - mean; vs += d * d; }
#pragma unroll
    for (int m = 32; m >= 1; m >>= 1) vs += __shfl_xor(vs, m, 64);
    if (lane == 0) red[4 + w] = vs;
    __syncthreads();
    const float var = (red[4] + red[5] + red[6] + red[7]) * (1.0f / 2048.0f);
    const float rstd = rsqrtf(var + 1e-5f);
    const int c0 = tid * 8;
    const float4 g0 = *(const float4*)(qg + c0);
    const float4 g1 = *(const float4*)(qg + c0 + 4);
    const float4 b0v = *(const float4*)(qb + c0);
    const float4 b1v = *(const float4*)(qb + c0 + 4);
    const float gA[8] = {g0.x, g0.y, g0.z, g0.w, g1.x, g1.y, g1.z, g1.w};
    const float bA[8] = {b0v.x, b0v.y, b0v.z, b0v.w, b1v.x, b1v.y, b1v.z, b1v.w};
    float y[8];
#pragma unroll
    for (int e = 0; e < 8; e++) y[e] = (v[e] - mean) * rstd * gA[e] + bA[e];
    const int h = c0 >> 7;
    bf16x8 ov;
#pragma unroll
    for (int e = 0; e < 8; e++) {
      const int c = c0 + e, d = c & 127, i = d & 63;
      const float part = __shfl_xor(y[e], 8, 64);
      const float rot = (d < 64) ? -part : part;
      ov[e] = (bf16)(y[e] * tcs[i] + rot * tsn[i]);
    }
    *(bf16x8*)(Qr + ((size_t)(b * 16 + h) * 2048 + tpos) * 128 + (c0 & 127)) = ov;
  } else if (bx < 5120) {
    // ---- LN + RoPE k: 4 rows/block, one 512-dim row per wave ----
    const int idx = bx - 4096;
    const int row = idx * 4 + w, b = row >> 11, tpos = row & 2047;
    {
      const float inv = exp2f((float)lane * (-LOG2_THETA / 64.0f));
      float sn, cs;
      sincosf((float)tpos * inv, &sn, &cs);
      ktab_c[w][lane] = cs; ktab_s[w][lane] = sn;
    }
    __syncthreads();
    const bf16* x = X + (size_t)row * 3072 + 2048;
    bf16x8 xi = *(const bf16x8*)(x + lane * 8);
    float v[8];
    float s = 0.0f;
#pragma unroll
    for (int e = 0; e < 8; e++) { v[e] = (float)xi[e]; s += v[e]; }
#pragma unroll
    for (int m = 32; m >= 1; m >>= 1) s += __shfl_xor(s, m, 64);
    const float mean = s * (1.0f / 512.0f);
    float vs = 0.0f;
#pragma unroll
    for (int e = 0; e < 8; e++) { float d = v[e] - mean; vs += d * d; }
#pragma unroll
    for (int m = 32; m >= 1; m >>= 1) vs += __shfl_xor(vs, m, 64);
    const float var = vs * (1.0f / 512.0f);
    const float rstd = rsqrtf(var + 1e-5f);
    const int c0 = lane * 8;
    const float4 g0 = *(const float4*)(kg + c0);
    const float4 g1 = *(const float4*)(kg + c0 + 4);
    const float4 b0v = *(const float4*)(kb + c0);
    const float4 b1v = *(const float4*)(kb + c0 + 4);
    const float gA[8] = {g0.x, g0.y, g0.z, g0.w, g1.x, g1.y, g1.z, g1.w};
    const float bA[8] = {b0v.x, b0v.y, b0v.z, b0v.w, b1v.x, b1v.y, b1v.z, b1v.w};
    float y[8];
#pragma unroll
    for (int e = 0; e < 8; e++) y[e] = (v[e] - mean) * rstd * gA[e] + bA[e];
    const int kv = c0 >> 7;
    bf16x8 ov;
#pragma unroll
    for (int e = 0; e < 8; e++) {
      const int c = c0 + e, d = c & 127, i = d & 63;
      const float part = __shfl_xor(y[e], 8, 64);
      const float rot = (d < 64) ? -part : part;
      ov[e] = (bf16)(y[e] * ktab_c[w][i] + rot * ktab_s[w][i]);
    }
    *(bf16x8*)(Kr + ((size_t)(b * 4 + kv) * 2048 + tpos) * 128 + (c0 & 127)) = ov;
  } else {
    // ---- V transpose ----
    const int idx = bx - 5120;
    const int b = idx >> 7, kv = (idx >> 5) & 3, t0 = (idx & 31) * 64;
#pragma unroll
    for (int i = 0; i < 4; i++) {
      const int c = i * 256 + tid;
      const int r = c >> 4, d8 = (c & 15) * 8;
      *(bf16x8*)&smt[r][d8] =
          *(const bf16x8*)(X + (size_t)(b * 2048 + t0 + r) * 3072 + 2560 + kv * 128 + d8);
    }
    __syncthreads();
#pragma unroll
    for (int i = 0; i < 4; i++) {
      const int c = i * 256 + tid;
      const int d = c >> 3, t8 = (c & 7) * 8;
      bf16x8 o;
#pragma unroll
      for (int j = 0; j < 8; j++) o[j] = smt[t8 + j][d];
      *(bf16x8*)(Vt + (size_t)((b * 4 + kv) * 128 + d) * 2048 + t0 + t8) = o;
    }
  }
}

// ============================================================
// Flash attention — R13: merged-pass k-loop on the R8 structure.
//  R8 ran two sequential passes (q-tiles 31-p and p), re-staging
//  k-tiles 0..p TWICE. Since qbB=p < qbA=31-p, B's k-range is a
//  prefix of A's: merge into ONE k-loop over 0..qbA computing A every
//  iteration and B while kt<=qbB (block-uniform predicate).
//   - tile iterations/block: 33 -> 32-p (avg 24.5, -26% barrier+
//     staging overhead); total MFMA work unchanged (33 tile-computes,
//     uniform across p -> no imbalance).
//   - shared-prefix K/V staged once: FETCH_SIZE down ~12%.
//   - iterations with A+B have 2x MFMA per staging wait.
//  Everything else is R8 verbatim: reg-staged prefetch (T14), same
//  swizzles, same Ps strip (wave-private; same-wave DS ops are
//  in-order, explicit lgkmcnt(0) between SM writes and PV reads).
//  LDS 44032; VGPR ~150 (2x aq, 2x o) — fine at 2 blocks/CU.
// ============================================================
__global__ __launch_bounds__(256) void flash_attn(
    const bf16* __restrict__ Q, const bf16* __restrict__ Kt,
    const bf16* __restrict__ Vt, bf16* __restrict__ O) {
  const int p = blockIdx.x;
  const int h = blockIdx.y, b = blockIdx.z;
  const int kv = h >> 2;
  const int tid = threadIdx.x;
  const int w = tid >> 6, lane = tid & 63, quad = lane >> 4, l15 = lane & 15;

  __shared__ bf16 Ks[64][128];
  __shared__ bf16 Vs[128][64];
  __shared__ bf16 Ps[4][16][88];

  const bf16* Kb = Kt + (size_t)(b * 4 + kv) * 2048 * 128;
  const bf16* Vb = Vt + (size_t)(b * 4 + kv) * 128 * 2048;

  // staging geometry (R8): thread (w,lane), chunk i in 0..3
  const int ksl = lane & 15, krt = lane >> 4;
  const int vsl = lane & 7,  vdt = lane >> 3;
  int kgo[4], vgo[4];
  bf16 *kwp[4], *vwp[4];
#pragma unroll
  for (int i = 0; i < 4; i++) {
    const int c = w * 4 + i;
    const int rt = c * 4 + krt;
    kgo[i] = rt * 128 + ksl * 8;
    kwp[i] = &Ks[rt][(ksl ^ (rt & 15)) * 8];
    const int d = c * 8 + vdt;
    vgo[i] = d * 2048 + vsl * 8;
    vwp[i] = &Vs[d][(vsl ^ (d & 7)) * 8];
  }

  const float cexp = 0.08838834764831845f * LOG2E;
  bf16x8 ones;
#pragma unroll
  for (int i = 0; i < 8; i++) ones[i] = (bf16)1.0f;

  const int qbA = 31 - p, qbB = p;
  const int q0A = qbA * 64, q0B = qbB * 64;
  const int nkt = qbA + 1;

  // both q-tiles' fragments in registers
  const bf16* QbA = Q + ((size_t)(b * 16 + h) * 2048 + q0A + w * 16 + l15) * 128;
  const bf16* QbB = Q + ((size_t)(b * 16 + h) * 2048 + q0B + w * 16 + l15) * 128;
  bf16x8 aqA[4], aqB[4];
#pragma unroll
  for (int kk = 0; kk < 4; kk++) {
    aqA[kk] = *(const bf16x8*)(QbA + kk * 32 + quad * 8);
    aqB[kk] = *(const bf16x8*)(QbB + kk * 32 + quad * 8);
  }

  f32x4 oA[9], oB[9];
#pragma unroll
  for (int dt = 0; dt < 9; dt++) { oA[dt] = (f32x4)0.0f; oB[dt] = (f32x4)0.0f; }

  // prefetch tile 0 into registers
  bf16x8 kreg[4], vreg[4];
#pragma unroll
  for (int i = 0; i < 4; i++) {
    kreg[i] = *(const bf16x8*)(Kb + kgo[i]);
    vreg[i] = *(const bf16x8*)(Vb + vgo[i]);
  }

#pragma unroll 1
  for (int kt = 0; kt < nkt; kt++) {
    const int k0 = kt * 64;
    __syncthreads();   // WAR: prev tile reads done; drains kt loads (landed)
#pragma unroll
    for (int i = 0; i < 4; i++) {
      *(bf16x8*)kwp[i] = kreg[i];
      *(bf16x8*)vwp[i] = vreg[i];
    }
    __syncthreads();   // RAW: Ks/Vs visible

    // issue NEXT tile's loads; latency hides under compute
    if (kt + 1 < nkt) {
      const size_t kb2 = (size_t)(k0 + 64);
#pragma unroll
      for (int i = 0; i < 4; i++) {
        kreg[i] = *(const bf16x8*)(Kb + kb2 * 128 + kgo[i]);
        vreg[i] = *(const bf16x8*)(Vb + kb2 + vgo[i]);
      }
    }

    // ================= q-tile A (every iteration) =================
    {
      f32x4 s4[4];
#pragma unroll
      for (int j = 0; j < 4; j++) {
        f32x4 acc = (f32x4)0.0f;
        const int n = j * 16 + l15;
#pragma unroll
        for (int kk = 0; kk < 4; kk++) {
          bf16x8 bk = *(const bf16x8*)(
              &Ks[0][0] + n * 128 + (((kk * 4 + quad) ^ l15) * 8));
          acc = __builtin_amdgcn_mfma_f32_16x16x32_bf16(aqA[kk], bk, acc, 0, 0, 0);
        }
        s4[j] = acc;
      }
      const bool diag = (kt == qbA);
      const int qrow_base = q0A + w * 16 + quad * 4;
#pragma unroll
      for (int j = 0; j < 4; j++) {
        const int kg = k0 + j * 16 + l15;
#pragma unroll
        for (int r = 0; r < 4; r++) {
          float pv = EXP2F(s4[j][r] * cexp);
          if (diag && kg > qrow_base + r) pv = 0.0f;
          Ps[w][quad * 4 + r][j * 16 + l15] = (bf16)pv;
        }
      }
      __asm__ volatile("s_waitcnt lgkmcnt(0)" ::: "memory");
#pragma unroll
      for (int kk = 0; kk < 2; kk++) {
        bf16x8 pa = *(const bf16x8*)&Ps[w][l15][kk * 32 + quad * 8];
#pragma unroll
        for (int dt = 0; dt < 8; dt++) {
          const int d = dt * 16 + l15;
          bf16x8 vb = *(const bf16x8*)(
              &Vs[0][0] + d * 64 + (((kk * 4 + quad) ^ (d & 7)) * 8));
          oA[dt] = __builtin_amdgcn_mfma_f32_16x16x32_bf16(pa, vb, oA[dt], 0, 0, 0);
        }
        oA[8] = __builtin_amdgcn_mfma_f32_16x16x32_bf16(pa, ones, oA[8], 0, 0, 0);
      }
    }

    // ============ q-tile B (prefix k-range, kt <= qbB) ============
    if (kt <= qbB) {
      f32x4 s4[4];
#pragma unroll
      for (int j = 0; j < 4; j++) {
        f32x4 acc = (f32x4)0.0f;
        const int n = j * 16 + l15;
#pragma unroll
        for (int kk = 0; kk < 4; kk++) {
          bf16x8 bk = *(const bf16x8*)(
              &Ks[0][0] + n * 128 + (((kk * 4 + quad) ^ l15) * 8));
          acc = __builtin_amdgcn_mfma_f32_16x16x32_bf16(aqB[kk], bk, acc, 0, 0, 0);
        }
        s4[j] = acc;
      }
      const bool diag = (kt == qbB);
      const int qrow_base = q0B + w * 16 + quad * 4;
      // WAR vs PV_A's Ps reads: same-wave DS ops retire in order, and
      // PV_A's reads have returned (their MFMAs consumed the data).
#pragma unroll
      for (int j = 0; j < 4; j++) {
        const int kg = k0 + j * 16 + l15;
#pragma unroll
        for (int r = 0; r < 4; r++) {
          float pv = EXP2F(s4[j][r] * cexp);
          if (diag && kg > qrow_base + r) pv = 0.0f;
          Ps[w][quad * 4 + r][j * 16 + l15] = (bf16)pv;
        }
      }
      __asm__ volatile("s_waitcnt lgkmcnt(0)" ::: "memory");
#pragma unroll
      for (int kk = 0; kk < 2; kk++) {
        bf16x8 pa = *(const bf16x8*)&Ps[w][l15][kk * 32 + quad * 8];
#pragma unroll
        for (int dt = 0; dt < 8; dt++) {
          const int d = dt * 16 + l15;
          bf16x8 vb = *(const bf16x8*)(
              &Vs[0][0] + d * 64 + (((kk * 4 + quad) ^ (d & 7)) * 8));
          oB[dt] = __builtin_amdgcn_mfma_f32_16x16x32_bf16(pa, vb, oB[dt], 0, 0, 0);
        }
        oB[8] = __builtin_amdgcn_mfma_f32_16x16x32_bf16(pa, ones, oB[8], 0, 0, 0);
      }
    }
  }

  // ---- epilogue: both q-tiles ----
  {
    bf16* Ob = O + ((size_t)(b * 2048 + q0A + w * 16 + quad * 4)) * 2048 + h * 128;
#pragma unroll
    for (int r = 0; r < 4; r++) {
      const float rinv = 1.0f / oA[8][r];
#pragma unroll
      for (int dt = 0; dt < 8; dt++)
        Ob[(size_t)r * 2048 + dt * 16 + l15] = (bf16)(oA[dt][r] * rinv);
    }
  }
  {
    bf16* Ob = O + ((size_t)(b * 2048 + q0B + w * 16 + quad * 4)) * 2048 + h * 128;
#pragma unroll
    for (int r = 0; r < 4; r++) {
      const float rinv = 1.0f / oB[8][r];
#pragma unroll
      for (int dt = 0; dt < 8; dt++)
        Ob[(size_t)r * 2048 + dt * 16 + l15] = (bf16)(oB[dt][r] * rinv);
    }
  }
}

// ============================================================
// Launcher — fp32 in/out, bf16 compute. 5 kernel launches.
// ws layout (bytes), total 88080384:
//   xb    bf16[4096x2048] : 0        .. 16777216  (reused as At)
//   wqkvb bf16[3072x2048] : 16777216 .. 29360128
//   wob   bf16[2048x2048] : 29360128 .. 37748736
//   qkvb  bf16[4096x3072] : 37748736 .. 62914560
//   Qr    bf16[2,16,2048,128] : 62914560 .. 79691776
//   Kr    bf16[2, 4,2048,128] : 79691776 .. 83886080
//   Vt    bf16[2, 4,128,2048] : 83886080 .. 88080384
// ============================================================
extern "C" void kernel_launch(void* const* d_in, const int* in_sizes, int n_in,
                              void* d_out, int out_size, void* d_ws, size_t ws_size,
                              hipStream_t stream) {
  const float* x   = (const float*)d_in[0];
  const float* wq  = (const float*)d_in[1];
  const float* bq  = (const float*)d_in[2];
  const float* wk  = (const float*)d_in[3];
  const float* bk  = (const float*)d_in[4];
  const float* wv  = (const float*)d_in[5];
  const float* bv  = (const float*)d_in[6];
  const float* wo  = (const float*)d_in[7];
  const float* bo  = (const float*)d_in[8];
  const float* qg  = (const float*)d_in[9];
  const float* qbt = (const float*)d_in[10];
  const float* kg  = (const float*)d_in[11];
  const float* kbt = (const float*)d_in[12];
  float* out = (float*)d_out;

  char* ws = (char*)d_ws;
  if (ws_size < (size_t)88080384) return;
  bf16* xb    = (bf16*)(ws);
  bf16* wqkvb = (bf16*)(ws + 16777216);
  bf16* wob   = (bf16*)(ws + 29360128);
  bf16* qkvb  = (bf16*)(ws + 37748736);
  bf16* Qr    = (bf16*)(ws + 62914560);
  bf16* Kr    = (bf16*)(ws + 79691776);
  bf16* Vt    = (bf16*)(ws + 83886080);
  bf16* At    = (bf16*)(ws);  // aliases xb — x dead after QKV gemm

  cast_all<<<9216, 256, 0, stream>>>(x, wq, wk, wv, wo, xb, wqkvb, wob);
  gemm_bt<bf16, true, true><<<dim3(32, 24), 256, 0, stream>>>(
      xb, wqkvb, bq, bk, bv, qkvb, 4096, 3072, 2048);
  fused_mid<<<5376, 256, 0, stream>>>(qkvb, qg, qbt, kg, kbt, Qr, Kr, Vt);
  flash_attn<<<dim3(16, 16, 2), 256, 0, stream>>>(Qr, Kr, Vt, At);
  gemm_bt<float, false, false><<<dim3(32, 16), 256, 0, stream>>>(
      At, wob, bo, nullptr, nullptr, out, 4096, 2048, 2048);
}